// Round 1
// baseline (1460.837 us; speedup 1.0000x reference)
//
#include <hip/hip_runtime.h>
#include <hip/hip_bf16.h>
#include <math.h>

// Problem constants
#define H_DIM 128
#define W_DIM 128
#define BATCH 4
#define NF 64
#define DG 8
#define TAPS 9

// Tiling
#define TH 8
#define TW 16
#define PIX (TH * TW)   // 128 pixels per block

// ---------------------------------------------------------------------------
// Transpose w_dcn [Cout=64][Cin=64][9] -> wT [Cin*9][Cout=64] so the deform
// kernel's 64-wide co loop reads contiguous scalar dwords (s_load_dwordx16).
// ---------------------------------------------------------------------------
__global__ void transpose_wdcn_kernel(const float* __restrict__ w,
                                      float* __restrict__ wT) {
    int idx = blockIdx.x * 256 + threadIdx.x;
    if (idx >= 64 * 64 * 9) return;
    int co   = idx & 63;
    int rest = idx >> 6;        // ci*9 + tap
    int tap  = rest % 9;
    int ci   = rest / 9;
    wT[idx] = w[(co * 64 + ci) * 9 + tap];
}

// ---------------------------------------------------------------------------
// Direct 3x3 SAME conv, NCHW. One thread = one pixel; NG wave-uniform cout
// groups of CPG channels each. Weights fetched via scalar path (uniform
// addresses -> s_load), inputs staged in LDS 8 channels at a time.
// ---------------------------------------------------------------------------
template<int CIN, int CPG, int NG, bool RELU, bool CONCAT>
__global__ __launch_bounds__(PIX * NG)
void conv3x3_kernel(const float* __restrict__ in0, const float* __restrict__ in1,
                    const float* __restrict__ w, const float* __restrict__ bias,
                    float* __restrict__ out, int COUT)
{
    constexpr int CI_BLK = 8;
    constexpr int ROWL = TH + 2;   // 10
    constexpr int COLL = TW + 2;   // 18
    constexpr int TILE_ELEMS = CI_BLK * ROWL * COLL;  // 1440
    __shared__ float s_in[CI_BLK][ROWL][COLL];

    const int b   = blockIdx.z;
    const int ty0 = blockIdx.y * TH;
    const int tx0 = blockIdx.x * TW;
    const int tid = threadIdx.x;
    const int p   = tid & (PIX - 1);
    const int grp = tid >> 7;                       // wave-uniform (PIX=128 = 2 waves)
    const int coBase = __builtin_amdgcn_readfirstlane(grp * CPG);
    const int ly = p / TW;
    const int lx = p % TW;
    const int y  = ty0 + ly;
    const int x  = tx0 + lx;

    float acc[CPG];
#pragma unroll
    for (int i = 0; i < CPG; ++i) acc[i] = 0.f;

    float* s_flat = &s_in[0][0][0];

    for (int cb = 0; cb < CIN; cb += CI_BLK) {
        __syncthreads();   // protect previous iteration's reads
        for (int i = tid; i < TILE_ELEMS; i += PIX * NG) {
            int ci = i / (ROWL * COLL);
            int r  = i % (ROWL * COLL);
            int yy = r / COLL;
            int xx = r % COLL;
            int gy = ty0 + yy - 1;
            int gx = tx0 + xx - 1;
            float v = 0.f;
            if (gy >= 0 && gy < H_DIM && gx >= 0 && gx < W_DIM) {
                int c = cb + ci;
                if (CONCAT) {
                    const float* src = (c < CIN / 2) ? in0 : in1;
                    int cc = (c < CIN / 2) ? c : (c - CIN / 2);
                    v = src[((b * (CIN / 2) + cc) * H_DIM + gy) * W_DIM + gx];
                } else {
                    v = in0[((b * CIN + c) * H_DIM + gy) * W_DIM + gx];
                }
            }
            s_flat[i] = v;
        }
        __syncthreads();

        for (int ci = 0; ci < CI_BLK; ++ci) {
            float v[9];
#pragma unroll
            for (int dy = 0; dy < 3; ++dy)
#pragma unroll
                for (int dx = 0; dx < 3; ++dx)
                    v[dy * 3 + dx] = s_in[ci][ly + dy][lx + dx];

            const float* wp = w + ((long)coBase * CIN + (cb + ci)) * 9;
#pragma unroll
            for (int co = 0; co < CPG; ++co) {
                const float* wc = wp + (long)co * CIN * 9;
#pragma unroll
                for (int k = 0; k < 9; ++k)
                    acc[co] = fmaf(v[k], wc[k], acc[co]);
            }
        }
    }

#pragma unroll
    for (int co = 0; co < CPG; ++co) {
        float r = acc[co] + bias[coBase + co];
        if (RELU) r = (r >= 0.f) ? r : 0.1f * r;
        out[((b * COUT + coBase + co) * H_DIM + y) * W_DIM + x] = r;
    }
}

// ---------------------------------------------------------------------------
// Modulated deformable conv v2 (3x3, stride 1, pad 1). One thread = one pixel,
// two wave-uniform g-groups (g 0..3 / 4..7) accumulate all 64 couts each,
// reduced via LDS at the end. Bilinear corner weights folded with mask.
// ---------------------------------------------------------------------------
__global__ __launch_bounds__(256)
void deform_kernel(const float* __restrict__ x, const float* __restrict__ om,
                   const float* __restrict__ wT, const float* __restrict__ bias,
                   float* __restrict__ out)
{
    constexpr int HW = H_DIM * W_DIM;
    __shared__ float s_red[64][PIX];   // 32 KiB

    const int b   = blockIdx.z;
    const int ty0 = blockIdx.y * TH;
    const int tx0 = blockIdx.x * TW;
    const int tid = threadIdx.x;
    const int p   = tid & (PIX - 1);
    const int grp = tid >> 7;
    const int gBase = __builtin_amdgcn_readfirstlane(grp * 4);
    const int ly = p / TW;
    const int lx = p % TW;
    const int y  = ty0 + ly;
    const int xw = tx0 + lx;
    const int pixoff = y * W_DIM + xw;

    float acc[64];
#pragma unroll
    for (int i = 0; i < 64; ++i) acc[i] = 0.f;

    for (int gi = 0; gi < 4; ++gi) {
        const int g = gBase + gi;
        const float* xg = x + ((long)b * 64 + g * 8) * HW;
        for (int tap = 0; tap < 9; ++tap) {
            const int och = g * 9 + tap;
            const float offy = om[((long)b * 216 + och) * HW + pixoff];
            const float offx = om[((long)b * 216 + 72 + och) * HW + pixoff];
            const float mraw = om[((long)b * 216 + 144 + och) * HW + pixoff];
            const float mask = 1.f / (1.f + __expf(-mraw));

            const float sy = offy + (float)(tap / 3 - 1) + (float)y;
            const float sx = offx + (float)(tap % 3 - 1) + (float)xw;
            const float fy = floorf(sy);
            const float fx = floorf(sx);
            const int y0 = (int)fy;
            const int x0 = (int)fx;
            const float ay = sy - fy;
            const float ax = sx - fx;

            const bool vy0 = (y0 >= 0) && (y0 < H_DIM);
            const bool vy1 = (y0 >= -1) && (y0 < H_DIM - 1);
            const bool vx0 = (x0 >= 0) && (x0 < W_DIM);
            const bool vx1 = (x0 >= -1) && (x0 < W_DIM - 1);

            float w00 = (1.f - ay) * (1.f - ax); if (!(vy0 && vx0)) w00 = 0.f;
            float w01 = (1.f - ay) * ax;         if (!(vy0 && vx1)) w01 = 0.f;
            float w10 = ay * (1.f - ax);         if (!(vy1 && vx0)) w10 = 0.f;
            float w11 = ay * ax;                 if (!(vy1 && vx1)) w11 = 0.f;
            w00 *= mask; w01 *= mask; w10 *= mask; w11 *= mask;

            const int iy0 = min(max(y0, 0), H_DIM - 1);
            const int iy1 = min(max(y0 + 1, 0), H_DIM - 1);
            const int ix0 = min(max(x0, 0), W_DIM - 1);
            const int ix1 = min(max(x0 + 1, 0), W_DIM - 1);
            const int i00 = iy0 * W_DIM + ix0;
            const int i01 = iy0 * W_DIM + ix1;
            const int i10 = iy1 * W_DIM + ix0;
            const int i11 = iy1 * W_DIM + ix1;

            for (int c = 0; c < 8; ++c) {
                const float* xc = xg + (long)c * HW;
                const float v = w00 * xc[i00] + w01 * xc[i01]
                              + w10 * xc[i10] + w11 * xc[i11];
                const float* wv = wT + (((g * 8 + c) * 9) + tap) * 64;  // uniform -> s_load
#pragma unroll
                for (int co = 0; co < 64; ++co)
                    acc[co] = fmaf(v, wv[co], acc[co]);
            }
        }
    }

    if (grp == 1) {
#pragma unroll
        for (int co = 0; co < 64; ++co) s_red[co][p] = acc[co];
    }
    __syncthreads();
    if (grp == 0) {
#pragma unroll
        for (int co = 0; co < 64; ++co) {
            float r = acc[co] + s_red[co][p] + bias[co];
            out[((long)b * 64 + co) * HW + pixoff] = r;
        }
    }
}

// ---------------------------------------------------------------------------
// Launcher
// ---------------------------------------------------------------------------
extern "C" void kernel_launch(void* const* d_in, const int* in_sizes, int n_in,
                              void* d_out, int out_size, void* d_ws, size_t ws_size,
                              hipStream_t stream) {
    const float* nbr  = (const float*)d_in[0];
    const float* ref  = (const float*)d_in[1];
    const float* w1   = (const float*)d_in[2];
    const float* b1   = (const float*)d_in[3];
    const float* w2   = (const float*)d_in[4];
    const float* b2   = (const float*)d_in[5];
    const float* wom  = (const float*)d_in[6];
    const float* bom  = (const float*)d_in[7];
    const float* wdcn = (const float*)d_in[8];
    const float* bdcn = (const float*)d_in[9];
    float* out = (float*)d_out;
    float* ws  = (float*)d_ws;

    // Workspace layout (floats). buf1 aliases the om buffer: buf1 is dead
    // once conv2 has consumed it, before conv3 writes om.
    const size_t OM_FLOATS  = (size_t)BATCH * 216 * H_DIM * W_DIM; // 14,155,776
    const size_t FEA_FLOATS = (size_t)BATCH * NF * H_DIM * W_DIM;  //  4,194,304
    float* buf1  = ws;                          // conv1 out (16 MB)
    float* bufom = ws;                          // conv3 out (56.6 MB), aliases buf1
    float* buf2  = ws + OM_FLOATS;              // conv2 out (16 MB)
    float* wT    = ws + OM_FLOATS + FEA_FLOATS; // 36,864 floats

    dim3 grid(W_DIM / TW, H_DIM / TH, BATCH);   // (8, 16, 4)

    transpose_wdcn_kernel<<<dim3((64 * 64 * 9 + 255) / 256), dim3(256), 0, stream>>>(wdcn, wT);

    // conv1: concat(nbr, ref) [128ch] -> 64, lrelu
    conv3x3_kernel<128, 32, 2, true, true><<<grid, dim3(256), 0, stream>>>(
        nbr, ref, w1, b1, buf1, 64);
    // conv2: 64 -> 64, lrelu
    conv3x3_kernel<64, 32, 2, true, false><<<grid, dim3(256), 0, stream>>>(
        buf1, nullptr, w2, b2, buf2, 64);
    // conv3: 64 -> 216 (offsets + mask), no activation
    conv3x3_kernel<64, 54, 4, false, false><<<grid, dim3(512), 0, stream>>>(
        buf2, nullptr, wom, bom, bufom, 216);
    // deformable conv
    deform_kernel<<<grid, dim3(256), 0, stream>>>(nbr, bufom, wT, bdcn, out);
}

// Round 2
// 262.116 us; speedup vs baseline: 5.5732x; 5.5732x over previous
//
#include <hip/hip_runtime.h>
#include <hip/hip_bf16.h>
#include <math.h>

#define H_DIM 128
#define W_DIM 128
#define BATCH 4
#define HW (H_DIM * W_DIM)

typedef __attribute__((ext_vector_type(8))) short bf16x8;
typedef __attribute__((ext_vector_type(4))) float f32x4;
typedef __attribute__((ext_vector_type(4))) unsigned int u32x4;

static __device__ __forceinline__ unsigned short f2bf(float f) {
    __hip_bfloat16 h = __float2bfloat16(f);   // RNE
    return *reinterpret_cast<unsigned short*>(&h);
}

// ---------------------------------------------------------------------------
// Build swizzled-NHWC bf16 concat input [B][H][W][128].
// Swizzle convention (all NHWC buffers): true channel-unit u (8 bf16 = 16B)
// of column x is stored at unit position u ^ ((x+1)&7). This makes the conv
// kernel's LDS fragment reads bank-conflict-free while staging stays a pure
// linear copy (swizzle pre-baked in global layout).
// ---------------------------------------------------------------------------
__global__ __launch_bounds__(256)
void prep_nhwc_kernel(const float* __restrict__ nbr, const float* __restrict__ ref,
                      unsigned short* __restrict__ dst) {
    const int y = blockIdx.x;
    const int b = blockIdx.y;
    const int x = threadIdx.x & 127;
    const int chalf = threadIdx.x >> 7;   // 0 or 1
    const int key = (x + 1) & 7;
    unsigned short* row = dst + ((size_t)(b * H_DIM + y) * W_DIM + x) * 128;
    for (int cc = 0; cc < 64; ++cc) {
        int c = chalf * 64 + cc;
        const float* src = (c < 64) ? nbr : ref;
        int cs = c & 63;
        float v = src[((size_t)(b * 64 + cs) * H_DIM + y) * W_DIM + x];
        int cpos = (((c >> 3) ^ key) << 3) | (c & 7);
        row[cpos] = f2bf(v);
    }
}

// ---------------------------------------------------------------------------
// Pack conv weights [COUT][CIN][3][3] fp32 -> MFMA B-fragment order bf16:
// dst[((ks*NCF + cf)*64 + lane)*8 + j] = w[co][ci][t] with
//   co = cf*16 + (lane&15), k = ks*32 + (lane>>4)*8 + j, t = k/CIN, ci = k%CIN.
// co >= COUT_real zero-padded.
// ---------------------------------------------------------------------------
__global__ void pack_w_kernel(const float* __restrict__ w, unsigned short* __restrict__ dst,
                              int COUT_real, int CIN, int NCF, int NKS) {
    int idx = blockIdx.x * 256 + threadIdx.x;
    int total = NKS * NCF * 64 * 8;
    if (idx >= total) return;
    int j    = idx & 7;
    int lane = (idx >> 3) & 63;
    int frag = idx >> 9;
    int cf   = frag % NCF;
    int ks   = frag / NCF;
    int co = cf * 16 + (lane & 15);
    int k  = ks * 32 + (lane >> 4) * 8 + j;
    int t  = k / CIN;
    int ci = k % CIN;
    float v = (co < COUT_real) ? w[((size_t)co * CIN + ci) * 9 + t] : 0.f;
    dst[idx] = f2bf(v);
}

// ---------------------------------------------------------------------------
// Transpose w_dcn [64][64][9] -> wT [ci*9+tap][64] for the deform kernel's
// scalar weight path.
// ---------------------------------------------------------------------------
__global__ void transpose_wdcn_kernel(const float* __restrict__ w,
                                      float* __restrict__ wT) {
    int idx = blockIdx.x * 256 + threadIdx.x;
    if (idx >= 64 * 64 * 9) return;
    int co   = idx & 63;
    int rest = idx >> 6;        // ci*9 + tap
    int tap  = rest % 9;
    int ci   = rest / 9;
    wT[idx] = w[(co * 64 + ci) * 9 + tap];
}

// ---------------------------------------------------------------------------
// Implicit-GEMM 3x3 SAME conv via bf16 MFMA.
// Block = one image row (128 px), 256 threads = 4 waves; wave w owns pixels
// [w*32, w*32+32) x BN=64 couts (cout-frag base blockIdx.y*4).
// LDS: raw input rows y-1..y+1, channel-contiguous, swizzled (see prep).
// K order: k = tap*CIN + ci. A-frag = im2col (pixel rows), B-frag = packed
// weights (co rows); D = A·B^T per gfx950 fragment layout (m89-verified).
// ---------------------------------------------------------------------------
template<int CIN, int NKS, int NCFT, bool RELU, bool NCHW216>
__global__ __launch_bounds__(256)
void conv_mfma_kernel(const unsigned short* __restrict__ in,   // swizzled NHWC bf16
                      const unsigned short* __restrict__ wpk,  // packed weight frags
                      const float* __restrict__ bias,
                      void* __restrict__ outv)
{
    static_assert(CIN % 32 == 0, "CIN must be multiple of 32");
    constexpr int ROWB = 132 * CIN * 2;      // bytes per dy row in LDS
    __shared__ __align__(16) char smem[3 * ROWB];

    const int rb  = blockIdx.x;        // b*H + y
    const int b   = rb >> 7;
    const int y   = rb & 127;
    const int cfb = blockIdx.y * 4;    // cout-frag base (conv3 only: gy 0..3)
    const int tid  = threadIdx.x;
    const int lane = tid & 63;
    const int wave = tid >> 6;
    const int l15  = lane & 15;
    const int q    = lane >> 4;
    const u32x4 zv = {0u, 0u, 0u, 0u};

    // ---- stage 3 input rows (linear copy; swizzle pre-baked in global) ----
    for (int dy = 0; dy < 3; ++dy) {
        int yy = y + dy - 1;
        char* dstrow = smem + dy * ROWB;
        if (yy >= 0 && yy < H_DIM) {
            const char* src = (const char*)(in + ((size_t)(b * H_DIM + yy) * W_DIM) * CIN);
            for (int i = tid * 16; i < 128 * CIN * 2; i += 256 * 16)
                *(u32x4*)(dstrow + CIN * 2 + i) = *(const u32x4*)(src + i);
            // zero halo columns gx=0 (x=-1) and gx=129 (x=128)
            for (int i = tid; i < 2 * (CIN / 8); i += 256) {
                int col = (i < CIN / 8) ? 0 : 129;
                int u   = i % (CIN / 8);
                *(u32x4*)(dstrow + (col * CIN + u * 8) * 2) = zv;
            }
        } else {
            for (int i = tid * 16; i < 130 * CIN * 2; i += 256 * 16)
                *(u32x4*)(dstrow + i) = zv;
        }
    }
    __syncthreads();

    // ---- K loop: no barriers, pure LDS reads + L2-hot weight loads ----
    f32x4 acc[2][4];
#pragma unroll
    for (int pf = 0; pf < 2; ++pf)
#pragma unroll
        for (int cf = 0; cf < 4; ++cf)
            acc[pf][cf] = (f32x4){0.f, 0.f, 0.f, 0.f};

    const int px0 = wave * 32;
#pragma unroll
    for (int ks = 0; ks < NKS; ++ks) {
        const int t   = ks / (CIN / 32);
        const int ci0 = (ks % (CIN / 32)) * 32;
        const int dy = t / 3, dx = t % 3;
        bf16x8 a[2];
#pragma unroll
        for (int pf = 0; pf < 2; ++pf) {
            int gx = px0 + pf * 16 + l15 + dx;
            int upos = ((ci0 >> 3) + q) ^ (gx & 7);
            a[pf] = *(const bf16x8*)(smem + dy * ROWB + (gx * CIN + upos * 8) * 2);
        }
        bf16x8 wfr[4];
#pragma unroll
        for (int cf = 0; cf < 4; ++cf)
            wfr[cf] = *(const bf16x8*)(wpk + ((size_t)(ks * NCFT + cfb + cf) * 64 + lane) * 8);
#pragma unroll
        for (int pf = 0; pf < 2; ++pf)
#pragma unroll
            for (int cf = 0; cf < 4; ++cf)
                acc[pf][cf] = __builtin_amdgcn_mfma_f32_16x16x32_bf16(
                    a[pf], wfr[cf], acc[pf][cf], 0, 0, 0);
    }

    // ---- epilogue ----
    if (!NCHW216) {
        // bf16 swizzled-NHWC store (COUT=64), feeds next conv's staging
        unsigned short* out = (unsigned short*)outv;
#pragma unroll
        for (int pf = 0; pf < 2; ++pf)
#pragma unroll
            for (int cf = 0; cf < 4; ++cf) {
                const int co = cf * 16 + l15;
                const float bv = bias[co];
#pragma unroll
                for (int r = 0; r < 4; ++r) {
                    int x = px0 + pf * 16 + q * 4 + r;
                    float v = acc[pf][cf][r] + bv;
                    if (RELU) v = (v >= 0.f) ? v : 0.1f * v;
                    int cpos = (((co >> 3) ^ ((x + 1) & 7)) << 3) | (co & 7);
                    out[((size_t)(b * H_DIM + y) * W_DIM + x) * 64 + cpos] = f2bf(v);
                }
            }
    } else {
        // fp32 NCHW store, 216 real couts (deform kernel consumes this)
        float* out = (float*)outv;
#pragma unroll
        for (int pf = 0; pf < 2; ++pf)
#pragma unroll
            for (int cf = 0; cf < 4; ++cf) {
                const int co = (cfb + cf) * 16 + l15;
                if (co < 216) {
                    const float bv = bias[co];
#pragma unroll
                    for (int r = 0; r < 4; ++r) {
                        int x = px0 + pf * 16 + q * 4 + r;
                        out[(size_t)(b * 216 + co) * HW + y * W_DIM + x] =
                            acc[pf][cf][r] + bv;
                    }
                }
            }
    }
}

// ---------------------------------------------------------------------------
// Modulated deformable conv v2 — unchanged from R0 (passed; profile next).
// ---------------------------------------------------------------------------
#define TH 8
#define TW 16
#define PIX (TH * TW)

__global__ __launch_bounds__(256)
void deform_kernel(const float* __restrict__ x, const float* __restrict__ om,
                   const float* __restrict__ wT, const float* __restrict__ bias,
                   float* __restrict__ out)
{
    __shared__ float s_red[64][PIX];   // 32 KiB

    const int b   = blockIdx.z;
    const int ty0 = blockIdx.y * TH;
    const int tx0 = blockIdx.x * TW;
    const int tid = threadIdx.x;
    const int p   = tid & (PIX - 1);
    const int grp = tid >> 7;
    const int gBase = __builtin_amdgcn_readfirstlane(grp * 4);
    const int ly = p / TW;
    const int lx = p % TW;
    const int y  = ty0 + ly;
    const int xw = tx0 + lx;
    const int pixoff = y * W_DIM + xw;

    float acc[64];
#pragma unroll
    for (int i = 0; i < 64; ++i) acc[i] = 0.f;

    for (int gi = 0; gi < 4; ++gi) {
        const int g = gBase + gi;
        const float* xg = x + ((size_t)b * 64 + g * 8) * HW;
        for (int tap = 0; tap < 9; ++tap) {
            const int och = g * 9 + tap;
            const float offy = om[((size_t)b * 216 + och) * HW + pixoff];
            const float offx = om[((size_t)b * 216 + 72 + och) * HW + pixoff];
            const float mraw = om[((size_t)b * 216 + 144 + och) * HW + pixoff];
            const float mask = 1.f / (1.f + __expf(-mraw));

            const float sy = offy + (float)(tap / 3 - 1) + (float)y;
            const float sx = offx + (float)(tap % 3 - 1) + (float)xw;
            const float fy = floorf(sy);
            const float fx = floorf(sx);
            const int y0 = (int)fy;
            const int x0 = (int)fx;
            const float ay = sy - fy;
            const float ax = sx - fx;

            const bool vy0 = (y0 >= 0) && (y0 < H_DIM);
            const bool vy1 = (y0 >= -1) && (y0 < H_DIM - 1);
            const bool vx0 = (x0 >= 0) && (x0 < W_DIM);
            const bool vx1 = (x0 >= -1) && (x0 < W_DIM - 1);

            float w00 = (1.f - ay) * (1.f - ax); if (!(vy0 && vx0)) w00 = 0.f;
            float w01 = (1.f - ay) * ax;         if (!(vy0 && vx1)) w01 = 0.f;
            float w10 = ay * (1.f - ax);         if (!(vy1 && vx0)) w10 = 0.f;
            float w11 = ay * ax;                 if (!(vy1 && vx1)) w11 = 0.f;
            w00 *= mask; w01 *= mask; w10 *= mask; w11 *= mask;

            const int iy0 = min(max(y0, 0), H_DIM - 1);
            const int iy1 = min(max(y0 + 1, 0), H_DIM - 1);
            const int ix0 = min(max(x0, 0), W_DIM - 1);
            const int ix1 = min(max(x0 + 1, 0), W_DIM - 1);
            const int i00 = iy0 * W_DIM + ix0;
            const int i01 = iy0 * W_DIM + ix1;
            const int i10 = iy1 * W_DIM + ix0;
            const int i11 = iy1 * W_DIM + ix1;

            for (int c = 0; c < 8; ++c) {
                const float* xc = xg + (size_t)c * HW;
                const float v = w00 * xc[i00] + w01 * xc[i01]
                              + w10 * xc[i10] + w11 * xc[i11];
                const float* wv = wT + (((g * 8 + c) * 9) + tap) * 64;  // uniform -> s_load
#pragma unroll
                for (int co = 0; co < 64; ++co)
                    acc[co] = fmaf(v, wv[co], acc[co]);
            }
        }
    }

    if (grp == 1) {
#pragma unroll
        for (int co = 0; co < 64; ++co) s_red[co][p] = acc[co];
    }
    __syncthreads();
    if (grp == 0) {
#pragma unroll
        for (int co = 0; co < 64; ++co) {
            float r = acc[co] + s_red[co][p] + bias[co];
            out[((size_t)b * 64 + co) * HW + pixoff] = r;
        }
    }
}

// ---------------------------------------------------------------------------
// Launcher. Workspace (bytes):
//   [0, 56.6M)        om fp32 (conv3 out; written AFTER the two aliased
//                     sub-buffers below are dead)
//     [0, 16.8M)      in1_nhwc bf16 (conv1 input; dead after conv1)
//     [16.8M, 25.2M)  conv1_out bf16 (dead after conv2)
//   [56.6M, 65.0M)    conv2_out bf16
//   [65.0M, ...)      wT, wpk1, wpk2, wpk3
// ---------------------------------------------------------------------------
extern "C" void kernel_launch(void* const* d_in, const int* in_sizes, int n_in,
                              void* d_out, int out_size, void* d_ws, size_t ws_size,
                              hipStream_t stream) {
    const float* nbr  = (const float*)d_in[0];
    const float* ref  = (const float*)d_in[1];
    const float* w1   = (const float*)d_in[2];
    const float* b1   = (const float*)d_in[3];
    const float* w2   = (const float*)d_in[4];
    const float* b2   = (const float*)d_in[5];
    const float* wom  = (const float*)d_in[6];
    const float* bom  = (const float*)d_in[7];
    const float* wdcn = (const float*)d_in[8];
    const float* bdcn = (const float*)d_in[9];
    float* out = (float*)d_out;
    char* W = (char*)d_ws;

    unsigned short* in1  = (unsigned short*)(W + 0);
    unsigned short* c1o  = (unsigned short*)(W + 16777216);
    unsigned short* c2o  = (unsigned short*)(W + 56623104);
    float*          om   = (float*)        (W + 0);
    float*          wT   = (float*)        (W + 65011712);
    unsigned short* wpk1 = (unsigned short*)(W + 65159168);
    unsigned short* wpk2 = (unsigned short*)(W + 65306624);
    unsigned short* wpk3 = (unsigned short*)(W + 65380352);

    prep_nhwc_kernel<<<dim3(H_DIM, BATCH), 256, 0, stream>>>(nbr, ref, in1);
    pack_w_kernel<<<288, 256, 0, stream>>>(w1, wpk1, 64, 128, 4, 36);
    pack_w_kernel<<<144, 256, 0, stream>>>(w2, wpk2, 64, 64, 4, 18);
    pack_w_kernel<<<576, 256, 0, stream>>>(wom, wpk3, 216, 64, 16, 18);
    transpose_wdcn_kernel<<<144, 256, 0, stream>>>(wdcn, wT);

    // conv1: concat(nbr,ref) 128ch -> 64, lrelu  (K = 9*128 = 1152, 36 ksteps)
    conv_mfma_kernel<128, 36, 4, true, false>
        <<<dim3(BATCH * H_DIM, 1), 256, 0, stream>>>(in1, wpk1, b1, (void*)c1o);
    // conv2: 64 -> 64, lrelu  (K = 576, 18 ksteps)
    conv_mfma_kernel<64, 18, 4, true, false>
        <<<dim3(BATCH * H_DIM, 1), 256, 0, stream>>>(c1o, wpk2, b2, (void*)c2o);
    // conv3: 64 -> 216 (couts padded to 256, gy=4), fp32 NCHW out
    conv_mfma_kernel<64, 18, 16, false, true>
        <<<dim3(BATCH * H_DIM, 4), 256, 0, stream>>>(c2o, wpk3, bom, (void*)om);

    deform_kernel<<<dim3(W_DIM / TW, H_DIM / TH, BATCH), 256, 0, stream>>>(
        nbr, om, wT, bdcn, out);
}

// Round 3
// 197.587 us; speedup vs baseline: 7.3934x; 1.3266x over previous
//
#include <hip/hip_runtime.h>
#include <hip/hip_bf16.h>
#include <math.h>

#define H_DIM 128
#define W_DIM 128
#define BATCH 4
#define HW (H_DIM * W_DIM)

typedef __attribute__((ext_vector_type(8))) short bf16x8;
typedef __attribute__((ext_vector_type(4))) float f32x4;
typedef __attribute__((ext_vector_type(4))) unsigned int u32x4;

static __device__ __forceinline__ unsigned short f2bf(float f) {
    __hip_bfloat16 h = __float2bfloat16(f);   // RNE
    return *reinterpret_cast<unsigned short*>(&h);
}
static __device__ __forceinline__ float bf2f(unsigned short u) {
    return __uint_as_float(((unsigned int)u) << 16);
}

// ---------------------------------------------------------------------------
// Build swizzled-NHWC bf16 concat input [B][H][W][128].
// Swizzle convention: channel-unit u (8 bf16 = 16B) of column x is stored at
// unit position u ^ ((x+1)&7) (bank-conflict-free LDS fragment reads; staging
// stays a linear copy).
// ---------------------------------------------------------------------------
__global__ __launch_bounds__(256)
void prep_nhwc_kernel(const float* __restrict__ nbr, const float* __restrict__ ref,
                      unsigned short* __restrict__ dst) {
    const int y = blockIdx.x;
    const int b = blockIdx.y;
    const int x = threadIdx.x & 127;
    const int chalf = threadIdx.x >> 7;   // 0 or 1
    const int key = (x + 1) & 7;
    unsigned short* row = dst + ((size_t)(b * H_DIM + y) * W_DIM + x) * 128;
    for (int cc = 0; cc < 64; ++cc) {
        int c = chalf * 64 + cc;
        const float* src = (c < 64) ? nbr : ref;
        int cs = c & 63;
        float v = src[((size_t)(b * 64 + cs) * H_DIM + y) * W_DIM + x];
        int cpos = (((c >> 3) ^ key) << 3) | (c & 7);
        row[cpos] = f2bf(v);
    }
}

// ---------------------------------------------------------------------------
// Plain NHWC bf16 copy of nbr: [B][HW][64]. LDS-transposed for coalescing.
// ---------------------------------------------------------------------------
__global__ __launch_bounds__(256)
void prep_nbr_nhwc_kernel(const float* __restrict__ nbr,
                          unsigned short* __restrict__ dst) {
    __shared__ float s[64][65];
    const int b  = blockIdx.y;
    const int p0 = blockIdx.x * 64;
    const int t  = threadIdx.x;
    for (int it = 0; it < 16; ++it) {
        int c = it * 4 + (t >> 6);
        s[c][t & 63] = nbr[(size_t)(b * 64 + c) * HW + p0 + (t & 63)];
    }
    __syncthreads();
    for (int it = 0; it < 2; ++it) {
        int idx = it * 256 + t;       // px*8 + unit
        int px = idx >> 3;
        int u  = idx & 7;
        bf16x8 v;
#pragma unroll
        for (int j = 0; j < 8; ++j)
            v[j] = (short)f2bf(s[u * 8 + j][px]);
        *(bf16x8*)(dst + ((size_t)(b * HW + p0 + px) * 64 + u * 8)) = v;
    }
}

// ---------------------------------------------------------------------------
// Pack conv weights [COUT][CIN][3][3] fp32 -> MFMA B-fragment order bf16:
// dst[((ks*NCF + cf)*64 + lane)*8 + j] = w[co][ci][t] with
//   co = cf*16 + (lane&15), k = ks*32 + (lane>>4)*8 + j, t = k/CIN, ci = k%CIN.
// ---------------------------------------------------------------------------
__global__ void pack_w_kernel(const float* __restrict__ w, unsigned short* __restrict__ dst,
                              int COUT_real, int CIN, int NCF, int NKS) {
    int idx = blockIdx.x * 256 + threadIdx.x;
    int total = NKS * NCF * 64 * 8;
    if (idx >= total) return;
    int j    = idx & 7;
    int lane = (idx >> 3) & 63;
    int frag = idx >> 9;
    int cf   = frag % NCF;
    int ks   = frag / NCF;
    int co = cf * 16 + (lane & 15);
    int k  = ks * 32 + (lane >> 4) * 8 + j;
    int t  = k / CIN;
    int ci = k % CIN;
    float v = (co < COUT_real) ? w[((size_t)co * CIN + ci) * 9 + t] : 0.f;
    dst[idx] = f2bf(v);
}

// ---------------------------------------------------------------------------
// Implicit-GEMM 3x3 SAME conv via bf16 MFMA (unchanged from R1).
// ---------------------------------------------------------------------------
template<int CIN, int NKS, int NCFT, bool RELU, bool NCHW216>
__global__ __launch_bounds__(256)
void conv_mfma_kernel(const unsigned short* __restrict__ in,   // swizzled NHWC bf16
                      const unsigned short* __restrict__ wpk,  // packed weight frags
                      const float* __restrict__ bias,
                      void* __restrict__ outv)
{
    static_assert(CIN % 32 == 0, "CIN must be multiple of 32");
    constexpr int ROWB = 132 * CIN * 2;      // bytes per dy row in LDS
    __shared__ __align__(16) char smem[3 * ROWB];

    const int rb  = blockIdx.x;        // b*H + y
    const int b   = rb >> 7;
    const int y   = rb & 127;
    const int cfb = blockIdx.y * 4;    // cout-frag base (conv3 only)
    const int tid  = threadIdx.x;
    const int lane = tid & 63;
    const int wave = tid >> 6;
    const int l15  = lane & 15;
    const int q    = lane >> 4;
    const u32x4 zv = {0u, 0u, 0u, 0u};

    for (int dy = 0; dy < 3; ++dy) {
        int yy = y + dy - 1;
        char* dstrow = smem + dy * ROWB;
        if (yy >= 0 && yy < H_DIM) {
            const char* src = (const char*)(in + ((size_t)(b * H_DIM + yy) * W_DIM) * CIN);
            for (int i = tid * 16; i < 128 * CIN * 2; i += 256 * 16)
                *(u32x4*)(dstrow + CIN * 2 + i) = *(const u32x4*)(src + i);
            for (int i = tid; i < 2 * (CIN / 8); i += 256) {
                int col = (i < CIN / 8) ? 0 : 129;
                int u   = i % (CIN / 8);
                *(u32x4*)(dstrow + (col * CIN + u * 8) * 2) = zv;
            }
        } else {
            for (int i = tid * 16; i < 130 * CIN * 2; i += 256 * 16)
                *(u32x4*)(dstrow + i) = zv;
        }
    }
    __syncthreads();

    f32x4 acc[2][4];
#pragma unroll
    for (int pf = 0; pf < 2; ++pf)
#pragma unroll
        for (int cf = 0; cf < 4; ++cf)
            acc[pf][cf] = (f32x4){0.f, 0.f, 0.f, 0.f};

    const int px0 = wave * 32;
#pragma unroll
    for (int ks = 0; ks < NKS; ++ks) {
        const int t   = ks / (CIN / 32);
        const int ci0 = (ks % (CIN / 32)) * 32;
        const int dy = t / 3, dx = t % 3;
        bf16x8 a[2];
#pragma unroll
        for (int pf = 0; pf < 2; ++pf) {
            int gx = px0 + pf * 16 + l15 + dx;
            int upos = ((ci0 >> 3) + q) ^ (gx & 7);
            a[pf] = *(const bf16x8*)(smem + dy * ROWB + (gx * CIN + upos * 8) * 2);
        }
        bf16x8 wfr[4];
#pragma unroll
        for (int cf = 0; cf < 4; ++cf)
            wfr[cf] = *(const bf16x8*)(wpk + ((size_t)(ks * NCFT + cfb + cf) * 64 + lane) * 8);
#pragma unroll
        for (int pf = 0; pf < 2; ++pf)
#pragma unroll
            for (int cf = 0; cf < 4; ++cf)
                acc[pf][cf] = __builtin_amdgcn_mfma_f32_16x16x32_bf16(
                    a[pf], wfr[cf], acc[pf][cf], 0, 0, 0);
    }

    if (!NCHW216) {
        unsigned short* out = (unsigned short*)outv;
#pragma unroll
        for (int pf = 0; pf < 2; ++pf)
#pragma unroll
            for (int cf = 0; cf < 4; ++cf) {
                const int co = cf * 16 + l15;
                const float bv = bias[co];
#pragma unroll
                for (int r = 0; r < 4; ++r) {
                    int x = px0 + pf * 16 + q * 4 + r;
                    float v = acc[pf][cf][r] + bv;
                    if (RELU) v = (v >= 0.f) ? v : 0.1f * v;
                    int cpos = (((co >> 3) ^ ((x + 1) & 7)) << 3) | (co & 7);
                    out[((size_t)(b * H_DIM + y) * W_DIM + x) * 64 + cpos] = f2bf(v);
                }
            }
    } else {
        float* out = (float*)outv;
#pragma unroll
        for (int pf = 0; pf < 2; ++pf)
#pragma unroll
            for (int cf = 0; cf < 4; ++cf) {
                const int co = (cfb + cf) * 16 + l15;
                if (co < 216) {
                    const float bv = bias[co];
#pragma unroll
                    for (int r = 0; r < 4; ++r) {
                        int x = px0 + pf * 16 + q * 4 + r;
                        out[(size_t)(b * 216 + co) * HW + y * W_DIM + x] =
                            acc[pf][cf][r] + bv;
                    }
                }
            }
    }
}

// ---------------------------------------------------------------------------
// Deformable conv v2 as implicit GEMM on MFMA.
// M=pixels, N=64 couts, K=576 with k = tap*64 + c_full.
// K-step ks (18 total): tap = ks>>1, channel half = ks&1.
// Lane q (lane>>4) picks group g = (ks&1)*4 + q; each lane builds one
// 8-channel bf16x8 A-fragment from one bilinear sample (4 x 16B gathers from
// bf16-NHWC x, L2-resident). Weights = pack_w_kernel frags (same k order).
// ---------------------------------------------------------------------------
__global__ __launch_bounds__(256, 2)
void deform_mfma_kernel(const unsigned short* __restrict__ xh,  // [B][HW][64] bf16
                        const float* __restrict__ om,           // [B][216][HW] f32
                        const unsigned short* __restrict__ wpk, // [18][4][64][8] bf16
                        const float* __restrict__ bias,
                        float* __restrict__ out)
{
    const int rb   = blockIdx.x;        // b*H + y
    const int b    = rb >> 7;
    const int y    = rb & 127;
    const int tid  = threadIdx.x;
    const int lane = tid & 63;
    const int wave = tid >> 6;
    const int l15  = lane & 15;
    const int q    = lane >> 4;
    const int px0  = wave * 32;

    const float* omb = om + (size_t)b * 216 * HW;
    const unsigned short* xb = xh + (size_t)b * HW * 64;

    f32x4 acc[2][4];
#pragma unroll
    for (int pf = 0; pf < 2; ++pf)
#pragma unroll
        for (int cf = 0; cf < 4; ++cf)
            acc[pf][cf] = (f32x4){0.f, 0.f, 0.f, 0.f};

#pragma unroll
    for (int ks = 0; ks < 18; ++ks) {
        const int tap = ks >> 1;
        const int g   = (ks & 1) * 4 + q;
        const int och = g * 9 + tap;
        const int dy  = tap / 3 - 1;
        const int dx  = tap % 3 - 1;

        bf16x8 a[2];
#pragma unroll
        for (int pf = 0; pf < 2; ++pf) {
            const int x   = px0 + pf * 16 + l15;
            const int pix = y * W_DIM + x;
            const float offy = omb[(size_t)och * HW + pix];
            const float offx = omb[(size_t)(72 + och) * HW + pix];
            const float mraw = omb[(size_t)(144 + och) * HW + pix];
            const float mask = 1.f / (1.f + __expf(-mraw));

            const float sy = offy + (float)(dy + y);
            const float sx = offx + (float)(dx + x);
            const float fy = floorf(sy);
            const float fx = floorf(sx);
            const int y0 = (int)fy;
            const int x0 = (int)fx;
            const float ay = sy - fy;
            const float ax = sx - fx;

            const bool vy0 = (y0 >= 0) && (y0 < H_DIM);
            const bool vy1 = (y0 >= -1) && (y0 < H_DIM - 1);
            const bool vx0 = (x0 >= 0) && (x0 < W_DIM);
            const bool vx1 = (x0 >= -1) && (x0 < W_DIM - 1);

            float w00 = (1.f - ay) * (1.f - ax); if (!(vy0 && vx0)) w00 = 0.f;
            float w01 = (1.f - ay) * ax;         if (!(vy0 && vx1)) w01 = 0.f;
            float w10 = ay * (1.f - ax);         if (!(vy1 && vx0)) w10 = 0.f;
            float w11 = ay * ax;                 if (!(vy1 && vx1)) w11 = 0.f;
            w00 *= mask; w01 *= mask; w10 *= mask; w11 *= mask;

            const int iy0 = min(max(y0, 0), H_DIM - 1);
            const int iy1 = min(max(y0 + 1, 0), H_DIM - 1);
            const int ix0 = min(max(x0, 0), W_DIM - 1);
            const int ix1 = min(max(x0 + 1, 0), W_DIM - 1);

            const unsigned short* gb = xb + g * 8;
            const bf16x8 c00 = *(const bf16x8*)(gb + (size_t)(iy0 * W_DIM + ix0) * 64);
            const bf16x8 c01 = *(const bf16x8*)(gb + (size_t)(iy0 * W_DIM + ix1) * 64);
            const bf16x8 c10 = *(const bf16x8*)(gb + (size_t)(iy1 * W_DIM + ix0) * 64);
            const bf16x8 c11 = *(const bf16x8*)(gb + (size_t)(iy1 * W_DIM + ix1) * 64);

            bf16x8 av;
#pragma unroll
            for (int j = 0; j < 8; ++j) {
                float v = w00 * bf2f((unsigned short)c00[j])
                        + w01 * bf2f((unsigned short)c01[j])
                        + w10 * bf2f((unsigned short)c10[j])
                        + w11 * bf2f((unsigned short)c11[j]);
                av[j] = (short)f2bf(v);
            }
            a[pf] = av;
        }

        bf16x8 wfr[4];
#pragma unroll
        for (int cf = 0; cf < 4; ++cf)
            wfr[cf] = *(const bf16x8*)(wpk + ((size_t)(ks * 4 + cf) * 64 + lane) * 8);
#pragma unroll
        for (int pf = 0; pf < 2; ++pf)
#pragma unroll
            for (int cf = 0; cf < 4; ++cf)
                acc[pf][cf] = __builtin_amdgcn_mfma_f32_16x16x32_bf16(
                    a[pf], wfr[cf], acc[pf][cf], 0, 0, 0);
    }

#pragma unroll
    for (int pf = 0; pf < 2; ++pf)
#pragma unroll
        for (int cf = 0; cf < 4; ++cf) {
            const int co = cf * 16 + l15;
            const float bv = bias[co];
#pragma unroll
            for (int r = 0; r < 4; ++r) {
                int x = px0 + pf * 16 + q * 4 + r;
                out[(size_t)(b * 64 + co) * HW + y * W_DIM + x] = acc[pf][cf][r] + bv;
            }
        }
}

// ---------------------------------------------------------------------------
// Launcher. Workspace (bytes):
//   [0, 56.6M)         om fp32 (conv3 out)
//     [0, 16.8M)       in1_nhwc bf16 (dead after conv1)
//     [16.8M, 25.2M)   conv1_out bf16 (dead after conv2)
//   [56.6M, 65.0M)     conv2_out bf16; ALIASED by nbrh bf16-NHWC (written
//                      after conv3 consumed c2o)
//   [65.0M, ...)       wpk1, wpk2, wpk3, wpkD
// ---------------------------------------------------------------------------
extern "C" void kernel_launch(void* const* d_in, const int* in_sizes, int n_in,
                              void* d_out, int out_size, void* d_ws, size_t ws_size,
                              hipStream_t stream) {
    const float* nbr  = (const float*)d_in[0];
    const float* ref  = (const float*)d_in[1];
    const float* w1   = (const float*)d_in[2];
    const float* b1   = (const float*)d_in[3];
    const float* w2   = (const float*)d_in[4];
    const float* b2   = (const float*)d_in[5];
    const float* wom  = (const float*)d_in[6];
    const float* bom  = (const float*)d_in[7];
    const float* wdcn = (const float*)d_in[8];
    const float* bdcn = (const float*)d_in[9];
    float* out = (float*)d_out;
    char* W = (char*)d_ws;

    unsigned short* in1  = (unsigned short*)(W + 0);
    unsigned short* c1o  = (unsigned short*)(W + 16777216);
    unsigned short* c2o  = (unsigned short*)(W + 56623104);
    unsigned short* nbrh = (unsigned short*)(W + 56623104);   // aliases c2o
    float*          om   = (float*)        (W + 0);
    unsigned short* wpk1 = (unsigned short*)(W + 65011712);
    unsigned short* wpk2 = (unsigned short*)(W + 65159168);
    unsigned short* wpk3 = (unsigned short*)(W + 65232896);
    unsigned short* wpkD = (unsigned short*)(W + 65527808);

    prep_nhwc_kernel<<<dim3(H_DIM, BATCH), 256, 0, stream>>>(nbr, ref, in1);
    pack_w_kernel<<<288, 256, 0, stream>>>(w1, wpk1, 64, 128, 4, 36);
    pack_w_kernel<<<144, 256, 0, stream>>>(w2, wpk2, 64, 64, 4, 18);
    pack_w_kernel<<<576, 256, 0, stream>>>(wom, wpk3, 216, 64, 16, 18);
    pack_w_kernel<<<144, 256, 0, stream>>>(wdcn, wpkD, 64, 64, 4, 18);

    // conv1: concat(nbr,ref) 128ch -> 64, lrelu
    conv_mfma_kernel<128, 36, 4, true, false>
        <<<dim3(BATCH * H_DIM, 1), 256, 0, stream>>>(in1, wpk1, b1, (void*)c1o);
    // conv2: 64 -> 64, lrelu
    conv_mfma_kernel<64, 18, 4, true, false>
        <<<dim3(BATCH * H_DIM, 1), 256, 0, stream>>>(c1o, wpk2, b2, (void*)c2o);
    // conv3: 64 -> 216 (couts padded to 256), fp32 NCHW out
    conv_mfma_kernel<64, 18, 16, false, true>
        <<<dim3(BATCH * H_DIM, 4), 256, 0, stream>>>(c2o, wpk3, bom, (void*)om);

    // bf16-NHWC copy of nbr for deform gathers (aliases dead c2o)
    prep_nbr_nhwc_kernel<<<dim3(HW / 64, BATCH), 256, 0, stream>>>(nbr, nbrh);

    deform_mfma_kernel<<<dim3(BATCH * H_DIM), 256, 0, stream>>>(
        nbrh, om, wpkD, bdcn, out);
}

// Round 4
// 166.653 us; speedup vs baseline: 8.7658x; 1.1856x over previous
//
#include <hip/hip_runtime.h>
#include <hip/hip_bf16.h>
#include <math.h>

#define H_DIM 128
#define W_DIM 128
#define BATCH 4
#define HW (H_DIM * W_DIM)

typedef __attribute__((ext_vector_type(8))) short bf16x8;
typedef __attribute__((ext_vector_type(4))) float f32x4;
typedef __attribute__((ext_vector_type(4))) unsigned int u32x4;

static __device__ __forceinline__ unsigned short f2bf(float f) {
    __hip_bfloat16 h = __float2bfloat16(f);   // RNE
    return *reinterpret_cast<unsigned short*>(&h);
}
static __device__ __forceinline__ float bf2f(unsigned short u) {
    return __uint_as_float(((unsigned int)u) << 16);
}

// ---------------------------------------------------------------------------
// Build swizzled-NHWC bf16 concat input [B][H][W][128] via LDS transpose.
// Swizzle convention: true channel-unit ut (8 bf16 = 16B) of column x stored
// at unit position (ut&8) | ((ut&7) ^ ((x+1)&7)).
// Block = 64 consecutive pixels (half an image row). Coalesced fp32 loads,
// vector bf16x8 stores.
// ---------------------------------------------------------------------------
__global__ __launch_bounds__(256)
void prep_nhwc_kernel(const float* __restrict__ nbr, const float* __restrict__ ref,
                      unsigned short* __restrict__ dst) {
    __shared__ float s[128][65];   // 33.3 KB
    const int b  = blockIdx.y;
    const int p0 = blockIdx.x * 64;          // aligned 64 px, same row y
    const int t  = threadIdx.x;
    const int px = t & 63;
#pragma unroll
    for (int it = 0; it < 32; ++it) {
        int c = it * 4 + (t >> 6);           // 0..127
        const float* src = (c < 64) ? nbr : ref;
        int cs = c & 63;
        s[c][px] = src[(size_t)(b * 64 + cs) * HW + p0 + px];
    }
    __syncthreads();
#pragma unroll
    for (int it = 0; it < 4; ++it) {
        int idx = it * 256 + t;              // p*16 + ut
        int p  = idx >> 4;
        int ut = idx & 15;
        int x  = (p0 + p) & 127;
        int key = (x + 1) & 7;
        int cpos = (ut & 8) | ((ut & 7) ^ key);
        bf16x8 v;
#pragma unroll
        for (int j = 0; j < 8; ++j)
            v[j] = (short)f2bf(s[ut * 8 + j][p]);
        *(bf16x8*)(dst + ((size_t)(b * HW + p0 + p) * 128 + cpos * 8)) = v;
    }
}

// ---------------------------------------------------------------------------
// Plain NHWC bf16 copy of nbr: [B][HW][64]. LDS-transposed for coalescing.
// ---------------------------------------------------------------------------
__global__ __launch_bounds__(256)
void prep_nbr_nhwc_kernel(const float* __restrict__ nbr,
                          unsigned short* __restrict__ dst) {
    __shared__ float s[64][65];
    const int b  = blockIdx.y;
    const int p0 = blockIdx.x * 64;
    const int t  = threadIdx.x;
#pragma unroll
    for (int it = 0; it < 16; ++it) {
        int c = it * 4 + (t >> 6);
        s[c][t & 63] = nbr[(size_t)(b * 64 + c) * HW + p0 + (t & 63)];
    }
    __syncthreads();
#pragma unroll
    for (int it = 0; it < 2; ++it) {
        int idx = it * 256 + t;       // px*8 + unit
        int px = idx >> 3;
        int u  = idx & 7;
        bf16x8 v;
#pragma unroll
        for (int j = 0; j < 8; ++j)
            v[j] = (short)f2bf(s[u * 8 + j][px]);
        *(bf16x8*)(dst + ((size_t)(b * HW + p0 + px) * 64 + u * 8)) = v;
    }
}

// ---------------------------------------------------------------------------
// Pack conv weights [COUT][CIN][3][3] fp32 -> MFMA B-fragment order bf16:
// dst[((ks*NCF + cf)*64 + lane)*8 + j] = w[co][ci][t] with
//   co = cf*16 + (lane&15), k = ks*32 + (lane>>4)*8 + j, t = k/CIN, ci = k%CIN.
// ---------------------------------------------------------------------------
__global__ void pack_w_kernel(const float* __restrict__ w, unsigned short* __restrict__ dst,
                              int COUT_real, int CIN, int NCF, int NKS) {
    int idx = blockIdx.x * 256 + threadIdx.x;
    int total = NKS * NCF * 64 * 8;
    if (idx >= total) return;
    int j    = idx & 7;
    int lane = (idx >> 3) & 63;
    int frag = idx >> 9;
    int cf   = frag % NCF;
    int ks   = frag / NCF;
    int co = cf * 16 + (lane & 15);
    int k  = ks * 32 + (lane >> 4) * 8 + j;
    int t  = k / CIN;
    int ci = k % CIN;
    float v = (co < COUT_real) ? w[((size_t)co * CIN + ci) * 9 + t] : 0.f;
    dst[idx] = f2bf(v);
}

// ---------------------------------------------------------------------------
// Implicit-GEMM 3x3 SAME conv via bf16 MFMA (unchanged).
// ---------------------------------------------------------------------------
template<int CIN, int NKS, int NCFT, bool RELU, bool NCHW216>
__global__ __launch_bounds__(256)
void conv_mfma_kernel(const unsigned short* __restrict__ in,   // swizzled NHWC bf16
                      const unsigned short* __restrict__ wpk,  // packed weight frags
                      const float* __restrict__ bias,
                      void* __restrict__ outv)
{
    static_assert(CIN % 32 == 0, "CIN must be multiple of 32");
    constexpr int ROWB = 132 * CIN * 2;      // bytes per dy row in LDS
    __shared__ __align__(16) char smem[3 * ROWB];

    const int rb  = blockIdx.x;        // b*H + y
    const int b   = rb >> 7;
    const int y   = rb & 127;
    const int cfb = blockIdx.y * 4;    // cout-frag base (conv3 only)
    const int tid  = threadIdx.x;
    const int lane = tid & 63;
    const int wave = tid >> 6;
    const int l15  = lane & 15;
    const int q    = lane >> 4;
    const u32x4 zv = {0u, 0u, 0u, 0u};

    for (int dy = 0; dy < 3; ++dy) {
        int yy = y + dy - 1;
        char* dstrow = smem + dy * ROWB;
        if (yy >= 0 && yy < H_DIM) {
            const char* src = (const char*)(in + ((size_t)(b * H_DIM + yy) * W_DIM) * CIN);
            for (int i = tid * 16; i < 128 * CIN * 2; i += 256 * 16)
                *(u32x4*)(dstrow + CIN * 2 + i) = *(const u32x4*)(src + i);
            for (int i = tid; i < 2 * (CIN / 8); i += 256) {
                int col = (i < CIN / 8) ? 0 : 129;
                int u   = i % (CIN / 8);
                *(u32x4*)(dstrow + (col * CIN + u * 8) * 2) = zv;
            }
        } else {
            for (int i = tid * 16; i < 130 * CIN * 2; i += 256 * 16)
                *(u32x4*)(dstrow + i) = zv;
        }
    }
    __syncthreads();

    f32x4 acc[2][4];
#pragma unroll
    for (int pf = 0; pf < 2; ++pf)
#pragma unroll
        for (int cf = 0; cf < 4; ++cf)
            acc[pf][cf] = (f32x4){0.f, 0.f, 0.f, 0.f};

    const int px0 = wave * 32;
#pragma unroll
    for (int ks = 0; ks < NKS; ++ks) {
        const int t   = ks / (CIN / 32);
        const int ci0 = (ks % (CIN / 32)) * 32;
        const int dy = t / 3, dx = t % 3;
        bf16x8 a[2];
#pragma unroll
        for (int pf = 0; pf < 2; ++pf) {
            int gx = px0 + pf * 16 + l15 + dx;
            int upos = ((ci0 >> 3) + q) ^ (gx & 7);
            a[pf] = *(const bf16x8*)(smem + dy * ROWB + (gx * CIN + upos * 8) * 2);
        }
        bf16x8 wfr[4];
#pragma unroll
        for (int cf = 0; cf < 4; ++cf)
            wfr[cf] = *(const bf16x8*)(wpk + ((size_t)(ks * NCFT + cfb + cf) * 64 + lane) * 8);
#pragma unroll
        for (int pf = 0; pf < 2; ++pf)
#pragma unroll
            for (int cf = 0; cf < 4; ++cf)
                acc[pf][cf] = __builtin_amdgcn_mfma_f32_16x16x32_bf16(
                    a[pf], wfr[cf], acc[pf][cf], 0, 0, 0);
    }

    if (!NCHW216) {
        unsigned short* out = (unsigned short*)outv;
#pragma unroll
        for (int pf = 0; pf < 2; ++pf)
#pragma unroll
            for (int cf = 0; cf < 4; ++cf) {
                const int co = cf * 16 + l15;
                const float bv = bias[co];
#pragma unroll
                for (int r = 0; r < 4; ++r) {
                    int x = px0 + pf * 16 + q * 4 + r;
                    float v = acc[pf][cf][r] + bv;
                    if (RELU) v = (v >= 0.f) ? v : 0.1f * v;
                    int cpos = (((co >> 3) ^ ((x + 1) & 7)) << 3) | (co & 7);
                    out[((size_t)(b * H_DIM + y) * W_DIM + x) * 64 + cpos] = f2bf(v);
                }
            }
    } else {
        float* out = (float*)outv;
#pragma unroll
        for (int pf = 0; pf < 2; ++pf)
#pragma unroll
            for (int cf = 0; cf < 4; ++cf) {
                const int co = (cfb + cf) * 16 + l15;
                if (co < 216) {
                    const float bv = bias[co];
#pragma unroll
                    for (int r = 0; r < 4; ++r) {
                        int x = px0 + pf * 16 + q * 4 + r;
                        out[(size_t)(b * 216 + co) * HW + y * W_DIM + x] =
                            acc[pf][cf][r] + bv;
                    }
                }
            }
    }
}

// ---------------------------------------------------------------------------
// Deformable conv v2 as implicit GEMM on MFMA (unchanged from R2).
// ---------------------------------------------------------------------------
__global__ __launch_bounds__(256, 2)
void deform_mfma_kernel(const unsigned short* __restrict__ xh,  // [B][HW][64] bf16
                        const float* __restrict__ om,           // [B][216][HW] f32
                        const unsigned short* __restrict__ wpk, // [18][4][64][8] bf16
                        const float* __restrict__ bias,
                        float* __restrict__ out)
{
    const int rb   = blockIdx.x;        // b*H + y
    const int b    = rb >> 7;
    const int y    = rb & 127;
    const int tid  = threadIdx.x;
    const int lane = tid & 63;
    const int wave = tid >> 6;
    const int l15  = lane & 15;
    const int q    = lane >> 4;
    const int px0  = wave * 32;

    const float* omb = om + (size_t)b * 216 * HW;
    const unsigned short* xb = xh + (size_t)b * HW * 64;

    f32x4 acc[2][4];
#pragma unroll
    for (int pf = 0; pf < 2; ++pf)
#pragma unroll
        for (int cf = 0; cf < 4; ++cf)
            acc[pf][cf] = (f32x4){0.f, 0.f, 0.f, 0.f};

#pragma unroll
    for (int ks = 0; ks < 18; ++ks) {
        const int tap = ks >> 1;
        const int g   = (ks & 1) * 4 + q;
        const int och = g * 9 + tap;
        const int dy  = tap / 3 - 1;
        const int dx  = tap % 3 - 1;

        bf16x8 a[2];
#pragma unroll
        for (int pf = 0; pf < 2; ++pf) {
            const int x   = px0 + pf * 16 + l15;
            const int pix = y * W_DIM + x;
            const float offy = omb[(size_t)och * HW + pix];
            const float offx = omb[(size_t)(72 + och) * HW + pix];
            const float mraw = omb[(size_t)(144 + och) * HW + pix];
            const float mask = 1.f / (1.f + __expf(-mraw));

            const float sy = offy + (float)(dy + y);
            const float sx = offx + (float)(dx + x);
            const float fy = floorf(sy);
            const float fx = floorf(sx);
            const int y0 = (int)fy;
            const int x0 = (int)fx;
            const float ay = sy - fy;
            const float ax = sx - fx;

            const bool vy0 = (y0 >= 0) && (y0 < H_DIM);
            const bool vy1 = (y0 >= -1) && (y0 < H_DIM - 1);
            const bool vx0 = (x0 >= 0) && (x0 < W_DIM);
            const bool vx1 = (x0 >= -1) && (x0 < W_DIM - 1);

            float w00 = (1.f - ay) * (1.f - ax); if (!(vy0 && vx0)) w00 = 0.f;
            float w01 = (1.f - ay) * ax;         if (!(vy0 && vx1)) w01 = 0.f;
            float w10 = ay * (1.f - ax);         if (!(vy1 && vx0)) w10 = 0.f;
            float w11 = ay * ax;                 if (!(vy1 && vx1)) w11 = 0.f;
            w00 *= mask; w01 *= mask; w10 *= mask; w11 *= mask;

            const int iy0 = min(max(y0, 0), H_DIM - 1);
            const int iy1 = min(max(y0 + 1, 0), H_DIM - 1);
            const int ix0 = min(max(x0, 0), W_DIM - 1);
            const int ix1 = min(max(x0 + 1, 0), W_DIM - 1);

            const unsigned short* gb = xb + g * 8;
            const bf16x8 c00 = *(const bf16x8*)(gb + (size_t)(iy0 * W_DIM + ix0) * 64);
            const bf16x8 c01 = *(const bf16x8*)(gb + (size_t)(iy0 * W_DIM + ix1) * 64);
            const bf16x8 c10 = *(const bf16x8*)(gb + (size_t)(iy1 * W_DIM + ix0) * 64);
            const bf16x8 c11 = *(const bf16x8*)(gb + (size_t)(iy1 * W_DIM + ix1) * 64);

            bf16x8 av;
#pragma unroll
            for (int j = 0; j < 8; ++j) {
                float v = w00 * bf2f((unsigned short)c00[j])
                        + w01 * bf2f((unsigned short)c01[j])
                        + w10 * bf2f((unsigned short)c10[j])
                        + w11 * bf2f((unsigned short)c11[j]);
                av[j] = (short)f2bf(v);
            }
            a[pf] = av;
        }

        bf16x8 wfr[4];
#pragma unroll
        for (int cf = 0; cf < 4; ++cf)
            wfr[cf] = *(const bf16x8*)(wpk + ((size_t)(ks * 4 + cf) * 64 + lane) * 8);
#pragma unroll
        for (int pf = 0; pf < 2; ++pf)
#pragma unroll
            for (int cf = 0; cf < 4; ++cf)
                acc[pf][cf] = __builtin_amdgcn_mfma_f32_16x16x32_bf16(
                    a[pf], wfr[cf], acc[pf][cf], 0, 0, 0);
    }

#pragma unroll
    for (int pf = 0; pf < 2; ++pf)
#pragma unroll
        for (int cf = 0; cf < 4; ++cf) {
            const int co = cf * 16 + l15;
            const float bv = bias[co];
#pragma unroll
            for (int r = 0; r < 4; ++r) {
                int x = px0 + pf * 16 + q * 4 + r;
                out[(size_t)(b * 64 + co) * HW + y * W_DIM + x] = acc[pf][cf][r] + bv;
            }
        }
}

// ---------------------------------------------------------------------------
// Launcher. Workspace (bytes):
//   [0, 56.6M)         om fp32 (conv3 out)
//     [0, 16.8M)       in1_nhwc bf16 (dead after conv1)
//     [16.8M, 25.2M)   conv1_out bf16 (dead after conv2)
//   [56.6M, 65.0M)     conv2_out bf16; ALIASED by nbrh bf16-NHWC (written
//                      after conv3 consumed c2o)
//   [65.0M, ...)       wpk1, wpk2, wpk3, wpkD
// ---------------------------------------------------------------------------
extern "C" void kernel_launch(void* const* d_in, const int* in_sizes, int n_in,
                              void* d_out, int out_size, void* d_ws, size_t ws_size,
                              hipStream_t stream) {
    const float* nbr  = (const float*)d_in[0];
    const float* ref  = (const float*)d_in[1];
    const float* w1   = (const float*)d_in[2];
    const float* b1   = (const float*)d_in[3];
    const float* w2   = (const float*)d_in[4];
    const float* b2   = (const float*)d_in[5];
    const float* wom  = (const float*)d_in[6];
    const float* bom  = (const float*)d_in[7];
    const float* wdcn = (const float*)d_in[8];
    const float* bdcn = (const float*)d_in[9];
    float* out = (float*)d_out;
    char* W = (char*)d_ws;

    unsigned short* in1  = (unsigned short*)(W + 0);
    unsigned short* c1o  = (unsigned short*)(W + 16777216);
    unsigned short* c2o  = (unsigned short*)(W + 56623104);
    unsigned short* nbrh = (unsigned short*)(W + 56623104);   // aliases c2o
    float*          om   = (float*)        (W + 0);
    unsigned short* wpk1 = (unsigned short*)(W + 65011712);
    unsigned short* wpk2 = (unsigned short*)(W + 65159168);
    unsigned short* wpk3 = (unsigned short*)(W + 65232896);
    unsigned short* wpkD = (unsigned short*)(W + 65527808);

    prep_nhwc_kernel<<<dim3(HW / 64, BATCH), 256, 0, stream>>>(nbr, ref, in1);
    pack_w_kernel<<<288, 256, 0, stream>>>(w1, wpk1, 64, 128, 4, 36);
    pack_w_kernel<<<144, 256, 0, stream>>>(w2, wpk2, 64, 64, 4, 18);
    pack_w_kernel<<<576, 256, 0, stream>>>(wom, wpk3, 216, 64, 16, 18);
    pack_w_kernel<<<144, 256, 0, stream>>>(wdcn, wpkD, 64, 64, 4, 18);

    // conv1: concat(nbr,ref) 128ch -> 64, lrelu
    conv_mfma_kernel<128, 36, 4, true, false>
        <<<dim3(BATCH * H_DIM, 1), 256, 0, stream>>>(in1, wpk1, b1, (void*)c1o);
    // conv2: 64 -> 64, lrelu
    conv_mfma_kernel<64, 18, 4, true, false>
        <<<dim3(BATCH * H_DIM, 1), 256, 0, stream>>>(c1o, wpk2, b2, (void*)c2o);
    // conv3: 64 -> 216 (couts padded to 256), fp32 NCHW out
    conv_mfma_kernel<64, 18, 16, false, true>
        <<<dim3(BATCH * H_DIM, 4), 256, 0, stream>>>(c2o, wpk3, bom, (void*)om);

    // bf16-NHWC copy of nbr for deform gathers (aliases dead c2o)
    prep_nbr_nhwc_kernel<<<dim3(HW / 64, BATCH), 256, 0, stream>>>(nbr, nbrh);

    deform_mfma_kernel<<<dim3(BATCH * H_DIM), 256, 0, stream>>>(
        nbrh, om, wpkD, bdcn, out);
}

// Round 5
// 145.262 us; speedup vs baseline: 10.0566x; 1.1473x over previous
//
#include <hip/hip_runtime.h>
#include <hip/hip_bf16.h>
#include <math.h>

#define H_DIM 128
#define W_DIM 128
#define BATCH 4
#define HW (H_DIM * W_DIM)

typedef __attribute__((ext_vector_type(8))) short bf16x8;
typedef __attribute__((ext_vector_type(4))) float f32x4;
typedef __attribute__((ext_vector_type(4))) unsigned int u32x4;

static __device__ __forceinline__ unsigned short f2bf(float f) {
    __hip_bfloat16 h = __float2bfloat16(f);   // RNE
    return *reinterpret_cast<unsigned short*>(&h);
}
static __device__ __forceinline__ float bf2f(unsigned short u) {
    return __uint_as_float(((unsigned int)u) << 16);
}

// ---------------------------------------------------------------------------
// Build swizzled-NHWC bf16 concat input [B][H][W][128] via LDS transpose.
// Swizzle: true channel-unit ut (8 bf16 = 16B) of column x stored at unit
// position (ut&8) | ((ut&7) ^ ((x+1)&7)).
// ---------------------------------------------------------------------------
__global__ __launch_bounds__(256)
void prep_nhwc_kernel(const float* __restrict__ nbr, const float* __restrict__ ref,
                      unsigned short* __restrict__ dst) {
    __shared__ float s[128][65];   // 33.3 KB
    const int b  = blockIdx.y;
    const int p0 = blockIdx.x * 64;          // aligned 64 px, same row y
    const int t  = threadIdx.x;
    const int px = t & 63;
#pragma unroll
    for (int it = 0; it < 32; ++it) {
        int c = it * 4 + (t >> 6);           // 0..127
        const float* src = (c < 64) ? nbr : ref;
        int cs = c & 63;
        s[c][px] = src[(size_t)(b * 64 + cs) * HW + p0 + px];
    }
    __syncthreads();
#pragma unroll
    for (int it = 0; it < 4; ++it) {
        int idx = it * 256 + t;              // p*16 + ut
        int p  = idx >> 4;
        int ut = idx & 15;
        int x  = (p0 + p) & 127;
        int key = (x + 1) & 7;
        int cpos = (ut & 8) | ((ut & 7) ^ key);
        bf16x8 v;
#pragma unroll
        for (int j = 0; j < 8; ++j)
            v[j] = (short)f2bf(s[ut * 8 + j][p]);
        *(bf16x8*)(dst + ((size_t)(b * HW + p0 + p) * 128 + cpos * 8)) = v;
    }
}

// ---------------------------------------------------------------------------
// Plain NHWC bf16 copy of nbr: [B][HW][64]. LDS-transposed for coalescing.
// ---------------------------------------------------------------------------
__global__ __launch_bounds__(256)
void prep_nbr_nhwc_kernel(const float* __restrict__ nbr,
                          unsigned short* __restrict__ dst) {
    __shared__ float s[64][65];
    const int b  = blockIdx.y;
    const int p0 = blockIdx.x * 64;
    const int t  = threadIdx.x;
#pragma unroll
    for (int it = 0; it < 16; ++it) {
        int c = it * 4 + (t >> 6);
        s[c][t & 63] = nbr[(size_t)(b * 64 + c) * HW + p0 + (t & 63)];
    }
    __syncthreads();
#pragma unroll
    for (int it = 0; it < 2; ++it) {
        int idx = it * 256 + t;       // px*8 + unit
        int px = idx >> 3;
        int u  = idx & 7;
        bf16x8 v;
#pragma unroll
        for (int j = 0; j < 8; ++j)
            v[j] = (short)f2bf(s[u * 8 + j][px]);
        *(bf16x8*)(dst + ((size_t)(b * HW + p0 + px) * 64 + u * 8)) = v;
    }
}

// ---------------------------------------------------------------------------
// Pack conv weights [COUT][CIN][3][3] fp32 -> MFMA B-fragment order bf16:
// dst[((ks*NCF + cf)*64 + lane)*8 + j] = w[co][ci][t] with
//   co = cf*16 + (lane&15), k = ks*32 + (lane>>4)*8 + j, t = k/CIN, ci = k%CIN.
// ---------------------------------------------------------------------------
__global__ void pack_w_kernel(const float* __restrict__ w, unsigned short* __restrict__ dst,
                              int COUT_real, int CIN, int NCF, int NKS) {
    int idx = blockIdx.x * 256 + threadIdx.x;
    int total = NKS * NCF * 64 * 8;
    if (idx >= total) return;
    int j    = idx & 7;
    int lane = (idx >> 3) & 63;
    int frag = idx >> 9;
    int cf   = frag % NCF;
    int ks   = frag / NCF;
    int co = cf * 16 + (lane & 15);
    int k  = ks * 32 + (lane >> 4) * 8 + j;
    int t  = k / CIN;
    int ci = k % CIN;
    float v = (co < COUT_real) ? w[((size_t)co * CIN + ci) * 9 + t] : 0.f;
    dst[idx] = f2bf(v);
}

// ---------------------------------------------------------------------------
// Implicit-GEMM 3x3 SAME conv via bf16 MFMA (conv1 / conv2 only now).
// ---------------------------------------------------------------------------
template<int CIN, int NKS, bool RELU>
__global__ __launch_bounds__(256)
void conv_mfma_kernel(const unsigned short* __restrict__ in,   // swizzled NHWC bf16
                      const unsigned short* __restrict__ wpk,  // packed weight frags
                      const float* __restrict__ bias,
                      unsigned short* __restrict__ out)
{
    static_assert(CIN % 32 == 0, "CIN must be multiple of 32");
    constexpr int ROWB = 132 * CIN * 2;      // bytes per dy row in LDS
    __shared__ __align__(16) char smem[3 * ROWB];

    const int rb  = blockIdx.x;        // b*H + y
    const int b   = rb >> 7;
    const int y   = rb & 127;
    const int tid  = threadIdx.x;
    const int lane = tid & 63;
    const int wave = tid >> 6;
    const int l15  = lane & 15;
    const int q    = lane >> 4;
    const u32x4 zv = {0u, 0u, 0u, 0u};

    for (int dy = 0; dy < 3; ++dy) {
        int yy = y + dy - 1;
        char* dstrow = smem + dy * ROWB;
        if (yy >= 0 && yy < H_DIM) {
            const char* src = (const char*)(in + ((size_t)(b * H_DIM + yy) * W_DIM) * CIN);
            for (int i = tid * 16; i < 128 * CIN * 2; i += 256 * 16)
                *(u32x4*)(dstrow + CIN * 2 + i) = *(const u32x4*)(src + i);
            for (int i = tid; i < 2 * (CIN / 8); i += 256) {
                int col = (i < CIN / 8) ? 0 : 129;
                int u   = i % (CIN / 8);
                *(u32x4*)(dstrow + (col * CIN + u * 8) * 2) = zv;
            }
        } else {
            for (int i = tid * 16; i < 130 * CIN * 2; i += 256 * 16)
                *(u32x4*)(dstrow + i) = zv;
        }
    }
    __syncthreads();

    f32x4 acc[2][4];
#pragma unroll
    for (int pf = 0; pf < 2; ++pf)
#pragma unroll
        for (int cf = 0; cf < 4; ++cf)
            acc[pf][cf] = (f32x4){0.f, 0.f, 0.f, 0.f};

    const int px0 = wave * 32;
#pragma unroll
    for (int ks = 0; ks < NKS; ++ks) {
        const int t   = ks / (CIN / 32);
        const int ci0 = (ks % (CIN / 32)) * 32;
        const int dy = t / 3, dx = t % 3;
        bf16x8 a[2];
#pragma unroll
        for (int pf = 0; pf < 2; ++pf) {
            int gx = px0 + pf * 16 + l15 + dx;
            int upos = ((ci0 >> 3) + q) ^ (gx & 7);
            a[pf] = *(const bf16x8*)(smem + dy * ROWB + (gx * CIN + upos * 8) * 2);
        }
        bf16x8 wfr[4];
#pragma unroll
        for (int cf = 0; cf < 4; ++cf)
            wfr[cf] = *(const bf16x8*)(wpk + ((size_t)(ks * 4 + cf) * 64 + lane) * 8);
#pragma unroll
        for (int pf = 0; pf < 2; ++pf)
#pragma unroll
            for (int cf = 0; cf < 4; ++cf)
                acc[pf][cf] = __builtin_amdgcn_mfma_f32_16x16x32_bf16(
                    a[pf], wfr[cf], acc[pf][cf], 0, 0, 0);
    }

#pragma unroll
    for (int pf = 0; pf < 2; ++pf)
#pragma unroll
        for (int cf = 0; cf < 4; ++cf) {
            const int co = cf * 16 + l15;
            const float bv = bias[co];
#pragma unroll
            for (int r = 0; r < 4; ++r) {
                int x = px0 + pf * 16 + q * 4 + r;
                float v = acc[pf][cf][r] + bv;
                if (RELU) v = (v >= 0.f) ? v : 0.1f * v;
                int cpos = (((co >> 3) ^ ((x + 1) & 7)) << 3) | (co & 7);
                out[((size_t)(b * H_DIM + y) * W_DIM + x) * 64 + cpos] = f2bf(v);
            }
        }
}

// ---------------------------------------------------------------------------
// FUSED conv3 (offset/mask conv, 216 couts) + modulated deformable conv.
// Block = one image row (b, y), 256 threads = 4 waves; wave owns 32 pixels.
// Phase 1: stage c2o rows y-1..y+1 (swizzled, 50.7 KB) -> conv3 into
//          acc[2][14] (224 padded couts) -> om row to LDS bf16 [216][132].
//          om never touches HBM (saves ~113 MB round-trip).
// Phase 2: deform conv for row y, offy/offx/mraw read from LDS.
// LDS union: staging (50688 B) | om (57024 B) -> 57 KB, 2 blocks/CU.
// ---------------------------------------------------------------------------
__global__ __launch_bounds__(256, 2)
void fused_om_deform_kernel(const unsigned short* __restrict__ in,   // c2o swizzled NHWC
                            const unsigned short* __restrict__ xh,   // nbr [B][HW][64] bf16
                            const unsigned short* __restrict__ wpk3, // [18][14][64][8]
                            const unsigned short* __restrict__ wpkD, // [18][4][64][8]
                            const float* __restrict__ bom,
                            const float* __restrict__ bdcn,
                            float* __restrict__ out)
{
    constexpr int CIN  = 64;
    constexpr int ROWB = 132 * CIN * 2;            // 16896 B per dy row
    __shared__ __align__(16) char smem[216 * 132 * 2];   // 57024 B union
    unsigned short* om_lds = (unsigned short*)smem;

    const int rb   = blockIdx.x;        // b*H + y
    const int b    = rb >> 7;
    const int y    = rb & 127;
    const int tid  = threadIdx.x;
    const int lane = tid & 63;
    const int wave = tid >> 6;
    const int l15  = lane & 15;
    const int q    = lane >> 4;
    const int px0  = wave * 32;
    const u32x4 zv = {0u, 0u, 0u, 0u};

    // ---- phase 1a: stage conv3 input rows (swizzled NHWC, linear copy) ----
    for (int dy = 0; dy < 3; ++dy) {
        int yy = y + dy - 1;
        char* dstrow = smem + dy * ROWB;
        if (yy >= 0 && yy < H_DIM) {
            const char* src = (const char*)(in + ((size_t)(b * H_DIM + yy) * W_DIM) * CIN);
            for (int i = tid * 16; i < 128 * CIN * 2; i += 256 * 16)
                *(u32x4*)(dstrow + CIN * 2 + i) = *(const u32x4*)(src + i);
            for (int i = tid; i < 2 * (CIN / 8); i += 256) {
                int col = (i < CIN / 8) ? 0 : 129;
                int u   = i % (CIN / 8);
                *(u32x4*)(dstrow + (col * CIN + u * 8) * 2) = zv;
            }
        } else {
            for (int i = tid * 16; i < 130 * CIN * 2; i += 256 * 16)
                *(u32x4*)(dstrow + i) = zv;
        }
    }
    __syncthreads();

    // ---- phase 1b: conv3, all 216 (pad 224) couts ----
    f32x4 acc[2][14];
#pragma unroll
    for (int pf = 0; pf < 2; ++pf)
#pragma unroll
        for (int cf = 0; cf < 14; ++cf)
            acc[pf][cf] = (f32x4){0.f, 0.f, 0.f, 0.f};

#pragma unroll
    for (int ks = 0; ks < 18; ++ks) {
        const int t   = ks >> 1;
        const int ci0 = (ks & 1) * 32;
        const int dy = t / 3, dx = t % 3;
        bf16x8 a[2];
#pragma unroll
        for (int pf = 0; pf < 2; ++pf) {
            int gx = px0 + pf * 16 + l15 + dx;
            int upos = ((ci0 >> 3) + q) ^ (gx & 7);
            a[pf] = *(const bf16x8*)(smem + dy * ROWB + (gx * CIN + upos * 8) * 2);
        }
#pragma unroll
        for (int cf = 0; cf < 14; ++cf) {
            bf16x8 wfr = *(const bf16x8*)(wpk3 + ((size_t)(ks * 14 + cf) * 64 + lane) * 8);
            acc[0][cf] = __builtin_amdgcn_mfma_f32_16x16x32_bf16(a[0], wfr, acc[0][cf], 0, 0, 0);
            acc[1][cf] = __builtin_amdgcn_mfma_f32_16x16x32_bf16(a[1], wfr, acc[1][cf], 0, 0, 0);
        }
    }
    __syncthreads();   // staging dead; om region aliases it

    // ---- phase 1c: om row -> LDS bf16 [216][132] ----
#pragma unroll
    for (int pf = 0; pf < 2; ++pf)
#pragma unroll
        for (int cf = 0; cf < 14; ++cf) {
            const int co = cf * 16 + l15;
            if (co < 216) {
                const float bv = bom[co];
#pragma unroll
                for (int r = 0; r < 4; ++r) {
                    int x = px0 + pf * 16 + q * 4 + r;
                    om_lds[co * 132 + x] = f2bf(acc[pf][cf][r] + bv);
                }
            }
        }
    __syncthreads();

    // ---- phase 2: deformable conv for row y ----
    const unsigned short* xb = xh + (size_t)b * HW * 64;

    f32x4 acc2[2][4];
#pragma unroll
    for (int pf = 0; pf < 2; ++pf)
#pragma unroll
        for (int cf = 0; cf < 4; ++cf)
            acc2[pf][cf] = (f32x4){0.f, 0.f, 0.f, 0.f};

#pragma unroll
    for (int ks = 0; ks < 18; ++ks) {
        const int tap = ks >> 1;
        const int g   = (ks & 1) * 4 + q;
        const int och = g * 9 + tap;
        const int dy  = tap / 3 - 1;
        const int dx  = tap % 3 - 1;

        bf16x8 a[2];
#pragma unroll
        for (int pf = 0; pf < 2; ++pf) {
            const int x = px0 + pf * 16 + l15;
            const float offy = bf2f(om_lds[(size_t)och * 132 + x]);
            const float offx = bf2f(om_lds[(size_t)(72 + och) * 132 + x]);
            const float mraw = bf2f(om_lds[(size_t)(144 + och) * 132 + x]);
            const float mask = 1.f / (1.f + __expf(-mraw));

            const float sy = offy + (float)(dy + y);
            const float sx = offx + (float)(dx + x);
            const float fy = floorf(sy);
            const float fx = floorf(sx);
            const int y0 = (int)fy;
            const int x0 = (int)fx;
            const float ay = sy - fy;
            const float ax = sx - fx;

            const bool vy0 = (y0 >= 0) && (y0 < H_DIM);
            const bool vy1 = (y0 >= -1) && (y0 < H_DIM - 1);
            const bool vx0 = (x0 >= 0) && (x0 < W_DIM);
            const bool vx1 = (x0 >= -1) && (x0 < W_DIM - 1);

            float w00 = (1.f - ay) * (1.f - ax); if (!(vy0 && vx0)) w00 = 0.f;
            float w01 = (1.f - ay) * ax;         if (!(vy0 && vx1)) w01 = 0.f;
            float w10 = ay * (1.f - ax);         if (!(vy1 && vx0)) w10 = 0.f;
            float w11 = ay * ax;                 if (!(vy1 && vx1)) w11 = 0.f;
            w00 *= mask; w01 *= mask; w10 *= mask; w11 *= mask;

            const int iy0 = min(max(y0, 0), H_DIM - 1);
            const int iy1 = min(max(y0 + 1, 0), H_DIM - 1);
            const int ix0 = min(max(x0, 0), W_DIM - 1);
            const int ix1 = min(max(x0 + 1, 0), W_DIM - 1);

            const unsigned short* gb = xb + g * 8;
            const bf16x8 c00 = *(const bf16x8*)(gb + (size_t)(iy0 * W_DIM + ix0) * 64);
            const bf16x8 c01 = *(const bf16x8*)(gb + (size_t)(iy0 * W_DIM + ix1) * 64);
            const bf16x8 c10 = *(const bf16x8*)(gb + (size_t)(iy1 * W_DIM + ix0) * 64);
            const bf16x8 c11 = *(const bf16x8*)(gb + (size_t)(iy1 * W_DIM + ix1) * 64);

            bf16x8 av;
#pragma unroll
            for (int j = 0; j < 8; ++j) {
                float v = w00 * bf2f((unsigned short)c00[j])
                        + w01 * bf2f((unsigned short)c01[j])
                        + w10 * bf2f((unsigned short)c10[j])
                        + w11 * bf2f((unsigned short)c11[j]);
                av[j] = (short)f2bf(v);
            }
            a[pf] = av;
        }

        bf16x8 wfr[4];
#pragma unroll
        for (int cf = 0; cf < 4; ++cf)
            wfr[cf] = *(const bf16x8*)(wpkD + ((size_t)(ks * 4 + cf) * 64 + lane) * 8);
#pragma unroll
        for (int pf = 0; pf < 2; ++pf)
#pragma unroll
            for (int cf = 0; cf < 4; ++cf)
                acc2[pf][cf] = __builtin_amdgcn_mfma_f32_16x16x32_bf16(
                    a[pf], wfr[cf], acc2[pf][cf], 0, 0, 0);
    }

#pragma unroll
    for (int pf = 0; pf < 2; ++pf)
#pragma unroll
        for (int cf = 0; cf < 4; ++cf) {
            const int co = cf * 16 + l15;
            const float bv = bdcn[co];
#pragma unroll
            for (int r = 0; r < 4; ++r) {
                int x = px0 + pf * 16 + q * 4 + r;
                out[(size_t)(b * 64 + co) * HW + y * W_DIM + x] = acc2[pf][cf][r] + bv;
            }
        }
}

// ---------------------------------------------------------------------------
// Launcher. Workspace (bytes), no aliasing needed (om lives in LDS now):
//   [0, 16.8M)        in1 swizzled-NHWC bf16
//   [16.8M, 25.2M)    c1o
//   [25.2M, 33.6M)    c2o
//   [33.6M, 42.0M)    nbrh bf16-NHWC
//   [42.0M, ...)      wpk1, wpk2, wpk3, wpkD
// ---------------------------------------------------------------------------
extern "C" void kernel_launch(void* const* d_in, const int* in_sizes, int n_in,
                              void* d_out, int out_size, void* d_ws, size_t ws_size,
                              hipStream_t stream) {
    const float* nbr  = (const float*)d_in[0];
    const float* ref  = (const float*)d_in[1];
    const float* w1   = (const float*)d_in[2];
    const float* b1   = (const float*)d_in[3];
    const float* w2   = (const float*)d_in[4];
    const float* b2   = (const float*)d_in[5];
    const float* wom  = (const float*)d_in[6];
    const float* bom  = (const float*)d_in[7];
    const float* wdcn = (const float*)d_in[8];
    const float* bdcn = (const float*)d_in[9];
    float* out = (float*)d_out;
    char* W = (char*)d_ws;

    unsigned short* in1  = (unsigned short*)(W + 0);
    unsigned short* c1o  = (unsigned short*)(W + 16777216);
    unsigned short* c2o  = (unsigned short*)(W + 25165824);
    unsigned short* nbrh = (unsigned short*)(W + 33554432);
    unsigned short* wpk1 = (unsigned short*)(W + 41943040);
    unsigned short* wpk2 = (unsigned short*)(W + 42090496);
    unsigned short* wpk3 = (unsigned short*)(W + 42164224);
    unsigned short* wpkD = (unsigned short*)(W + 42422272);

    prep_nhwc_kernel<<<dim3(HW / 64, BATCH), 256, 0, stream>>>(nbr, ref, in1);
    pack_w_kernel<<<288, 256, 0, stream>>>(w1, wpk1, 64, 128, 4, 36);
    pack_w_kernel<<<144, 256, 0, stream>>>(w2, wpk2, 64, 64, 4, 18);
    pack_w_kernel<<<504, 256, 0, stream>>>(wom, wpk3, 216, 64, 14, 18);
    pack_w_kernel<<<144, 256, 0, stream>>>(wdcn, wpkD, 64, 64, 4, 18);
    prep_nbr_nhwc_kernel<<<dim3(HW / 64, BATCH), 256, 0, stream>>>(nbr, nbrh);

    // conv1: concat(nbr,ref) 128ch -> 64, lrelu
    conv_mfma_kernel<128, 36, true>
        <<<dim3(BATCH * H_DIM), 256, 0, stream>>>(in1, wpk1, b1, c1o);
    // conv2: 64 -> 64, lrelu
    conv_mfma_kernel<64, 18, true>
        <<<dim3(BATCH * H_DIM), 256, 0, stream>>>(c1o, wpk2, b2, c2o);

    // fused conv3 + deformable conv
    fused_om_deform_kernel<<<dim3(BATCH * H_DIM), 256, 0, stream>>>(
        c2o, nbrh, wpk3, wpkD, bom, bdcn, out);
}